// Round 6
// baseline (97.168 us; speedup 1.0000x reference)
//
#include <hip/hip_runtime.h>
#include <math.h>

#define EPSF 1e-6f
constexpr int Bn  = 32;
constexpr int CLS = 16;
constexpr int DST = 8;
constexpr int Cc  = 64, Hh = 16, Wd = 16;
constexpr int CHW  = Cc * Hh * Wd;   // 16384
constexpr int CHW2 = 2 * CHW;        // 32768
constexpr int CHW4 = 4 * CHW;        // 65536
constexpr int KCHUNK = 64;           // K1 chunks per class

// fast log-sigmoid: -log(1+exp(-x)) = min(x,0) - log(1+exp(-|x|))
__device__ __forceinline__ float fls(float x) {
    float t = __expf(-fabsf(x));
    return fminf(x, 0.0f) - __logf(1.0f + t);
}

__device__ __forceinline__ float4 ld4(const float* p) { return *(const float4*)p; }
__device__ __forceinline__ void st4(float* p, float4 v) { *(float4*)p = v; }

// ---------------------------------------------------------------------------
// K1: 1024 blocks = (class c, chunk). Per thread (c, e):
//   - inline segment-sum over batch (block-uniform label match) -> xle0, xle1
//     and xy_out[c, e] / xy_out[c, CHW+e]  (no separate kA pass)
//   - inline log-sigmoid of miu (no precompute arrays)
//   - means_theta[c,e], lmm[c,e], le_norm partials (block-reduced, no atomics)
// ---------------------------------------------------------------------------
__global__ __launch_bounds__(256) void K1(
    const float* __restrict__ x, const int* __restrict__ labels,
    const float* __restrict__ X_LEs, const float* __restrict__ X_LEs_xy,
    const float* __restrict__ X_weights, const float* __restrict__ sigmas,
    const float* __restrict__ w1, const float* __restrict__ miu,
    const float* __restrict__ tao,
    float* __restrict__ xy_out, float* __restrict__ means_theta,
    float* __restrict__ lmm, float* __restrict__ partials)
{
    const int c     = blockIdx.x >> 6;                 // [0,16)
    const int chunk = blockIdx.x & 63;
    const int e     = chunk * 256 + threadIdx.x;       // [0, CHW)

    __shared__ int lab_sh[Bn];
    if (threadIdx.x < Bn) lab_sh[threadIdx.x] = labels[threadIdx.x];
    __syncthreads();

    // ---- inline segment sums for this (c, e) and (c, CHW+e) ----
    float acc_tm0 = 0.f, acc_tm1 = 0.f, acc_xy0 = 0.f, acc_xy1 = 0.f, cnt = 0.f;
    for (int b = 0; b < Bn; ++b) {
        if (lab_sh[b] == c) {          // block-uniform branch
            const float* xb = x + b * CHW4;
            acc_tm0 += xb[e];
            acc_tm1 += xb[CHW + e];
            acc_xy0 += xb[CHW2 + e];
            acc_xy1 += xb[CHW2 + CHW + e];
            cnt += 1.0f;
        }
    }
    const float xw = X_weights[c] + cnt;

    const float xle0 = (X_LEs[c * CHW2 + e]       + acc_tm0) / xw;
    const float xle1 = (X_LEs[c * CHW2 + CHW + e] + acc_tm1) / xw;   // mag
    xy_out[c * CHW2 + e]       = (X_LEs_xy[c * CHW2 + e]       + acc_xy0) / xw;
    xy_out[c * CHW2 + CHW + e] = (X_LEs_xy[c * CHW2 + CHW + e] + acc_xy1) / xw;

    // ---- stage-B math ----
    const float sig    = sigmas[c];
    const float sig_sq = sig * sig;

    float w1sqv[DST];
    float ssum = 0.f;
#pragma unroll
    for (int d = 0; d < DST; ++d) { const float t = w1[d]; w1sqv[d] = t * t; ssum += t * t; }
    const float ssum_r = 1.0f / ssum;

    const float ls0  = fls(xle0);
    const float ls1  = fls(xle1);
    const float ls1e = fls(xle1 + EPSF);

    float mt = 0.f, mm = 0.f;
    float ln_d[DST];

#pragma unroll
    for (int d = 0; d < DST; ++d) {
        const float ta     = tao[d];
        const float tao_sq = ta * ta;
        const float den_r  = 1.0f / (sig_sq + tao_sq);
        const float a      = tao_sq * den_r;
        const float b      = sig_sq * den_r;
        const float wn     = w1sqv[d] * ssum_r;

        const float m0   = miu[d * CHW2 + e];
        const float m1   = miu[d * CHW2 + CHW + e];
        const float lm0  = fls(m0);
        const float lm1  = fls(m1);
        const float lm1e = fls(m1 + EPSF);

        mt += (xle1 * a + m0 * b) * wn;
        mm += __expf((a * ls1e + b * lm1e) * wn);

        const float d0 = ls0 - lm0, d1 = ls1 - lm1;
        ln_d[d] = d0 * d0 + d1 * d1;
    }

    means_theta[c * CHW + e] = mt;
    lmm        [c * CHW + e] = __logf(mm + EPSF);

    // wave shuffle reduce -> cross-wave LDS reduce -> one store per d
    __shared__ float sh[4][DST];
    const int wave = threadIdx.x >> 6;
    const int lane = threadIdx.x & 63;
#pragma unroll
    for (int d = 0; d < DST; ++d) {
        float v = ln_d[d];
        v += __shfl_down(v, 32);
        v += __shfl_down(v, 16);
        v += __shfl_down(v, 8);
        v += __shfl_down(v, 4);
        v += __shfl_down(v, 2);
        v += __shfl_down(v, 1);
        if (lane == 0) sh[wave][d] = v;
    }
    __syncthreads();
    if (threadIdx.x < DST) {
        const int d = threadIdx.x;
        const float s = sh[0][d] + sh[1][d] + sh[2][d] + sh[3][d];
        partials[(d * CLS + c) * KCHUNK + chunk] = s;
    }
}

// ---------------------------------------------------------------------------
// K2: blocks [0,512): kD float4 — dist over (c,b,e4), min over c.
//     block 512:      kC — loss[d], second-stage reduce of partials.
// ---------------------------------------------------------------------------
__global__ __launch_bounds__(256) void K2(
    const float* __restrict__ x, const float* __restrict__ weight,
    const float* __restrict__ means_theta, const float* __restrict__ lmm,
    const float* __restrict__ xy_out,
    const int* __restrict__ labels, const float* __restrict__ X_weights,
    const float* __restrict__ sigmas, const float* __restrict__ tao,
    const float* __restrict__ partials,
    float* __restrict__ out, float* __restrict__ loss_out)
{
    if (blockIdx.x == 512) {
        const int t = threadIdx.x;
        if (t >= 128) return;
        const int d = t >> 4;
        const int c = t & 15;

        const float* p = partials + (d * CLS + c) * KCHUNK;
        float le = 0.f;
#pragma unroll
        for (int k = 0; k < KCHUNK; ++k) le += p[k];

        float cnt = 0.f;
        for (int b = 0; b < Bn; ++b) cnt += (labels[b] == c) ? 1.f : 0.f;
        const float xw = X_weights[c] + cnt;

        const float sig = sigmas[c], ssq = sig * sig;
        const float ta  = tao[d],    tsq = ta * ta;
        const float den = tsq + ssq;

        const float term1 = ssq / (den * den);
        const float term2 = ssq * le;
        const float term3 = (2.0f * (float)CHW) * (tsq * tsq - ssq * ssq) / xw;

        float v = term1 * (term2 + term3);
        v += __shfl_xor(v, 8);
        v += __shfl_xor(v, 4);
        v += __shfl_xor(v, 2);
        v += __shfl_xor(v, 1);
        if (c == 0) loss_out[d] = v * (1.0f / 16.0f);
        return;
    }

    const int idx = blockIdx.x * 256 + threadIdx.x;   // [0, 131072)
    const int b  = idx >> 12;                          // [0,32)
    const int e4 = (idx & 4095) << 2;                  // [0, CHW) step 4

    const float w0 = weight[0], w1w = weight[1], w2 = weight[2];
    const float w0sq = w0 * w0, w1sq = w1w * w1w, w2sq = w2 * w2;

    const float* xb = x + b * CHW4;
    const float4 xt0 = ld4(xb + e4);
    const float4 xt1 = ld4(xb + CHW + e4);
    const float4 xx0 = ld4(xb + CHW2 + e4);
    const float4 xx1 = ld4(xb + CHW2 + CHW + e4);
    float4 lx;
    lx.x = __logf(xt1.x); lx.y = __logf(xt1.y);
    lx.z = __logf(xt1.z); lx.w = __logf(xt1.w);

    float4 m = { __builtin_inff(), __builtin_inff(), __builtin_inff(), __builtin_inff() };
#pragma unroll
    for (int c = 0; c < CLS; ++c) {
        const float4 mtv = ld4(means_theta + c * CHW + e4);
        const float4 lmv = ld4(lmm + c * CHW + e4);
        const float4 y0  = ld4(xy_out + c * CHW2 + e4);
        const float4 y1  = ld4(xy_out + c * CHW2 + CHW + e4);
        {
            const float dr = fabsf(xt0.x - mtv.x);
            const float da = fabsf(lx.x - lmv.x);
            const float d0 = xx0.x - y0.x, d1 = xx1.x - y1.x;
            m.x = fminf(m.x, w0sq * dr + w1sq * da + w2sq * (d0 * d0 + d1 * d1));
        }
        {
            const float dr = fabsf(xt0.y - mtv.y);
            const float da = fabsf(lx.y - lmv.y);
            const float d0 = xx0.y - y0.y, d1 = xx1.y - y1.y;
            m.y = fminf(m.y, w0sq * dr + w1sq * da + w2sq * (d0 * d0 + d1 * d1));
        }
        {
            const float dr = fabsf(xt0.z - mtv.z);
            const float da = fabsf(lx.z - lmv.z);
            const float d0 = xx0.z - y0.z, d1 = xx1.z - y1.z;
            m.z = fminf(m.z, w0sq * dr + w1sq * da + w2sq * (d0 * d0 + d1 * d1));
        }
        {
            const float dr = fabsf(xt0.w - mtv.w);
            const float da = fabsf(lx.w - lmv.w);
            const float d0 = xx0.w - y0.w, d1 = xx1.w - y1.w;
            m.w = fminf(m.w, w0sq * dr + w1sq * da + w2sq * (d0 * d0 + d1 * d1));
        }
    }
    st4(out + b * CHW + e4, m);
}

// ---------------------------------------------------------------------------
extern "C" void kernel_launch(void* const* d_in, const int* in_sizes, int n_in,
                              void* d_out, int out_size, void* d_ws, size_t ws_size,
                              hipStream_t stream)
{
    const float* x         = (const float*)d_in[0];
    const int*   labels    = (const int*)  d_in[1];
    const float* X_LEs     = (const float*)d_in[2];
    const float* X_LEs_xy  = (const float*)d_in[3];
    const float* X_weights = (const float*)d_in[4];
    const float* sigmas    = (const float*)d_in[5];
    const float* w1        = (const float*)d_in[6];
    const float* miu       = (const float*)d_in[7];
    const float* tao       = (const float*)d_in[8];
    const float* weight    = (const float*)d_in[9];

    float* ws          = (float*)d_ws;
    float* xy_out      = ws;                      // 524288 floats
    float* means_theta = ws + 524288;             // 262144
    float* lmm         = ws + 786432;             // 262144
    float* partials    = ws + 1048576;            // 8192 (8*16*64)

    float* out  = (float*)d_out;       // 524288
    float* loss = out + Bn * CHW;      // 8

    hipLaunchKernelGGL(K1, dim3(CLS * KCHUNK), dim3(256), 0, stream,
                       x, labels, X_LEs, X_LEs_xy, X_weights, sigmas,
                       w1, miu, tao,
                       xy_out, means_theta, lmm, partials);
    hipLaunchKernelGGL(K2, dim3(512 + 1), dim3(256), 0, stream,
                       x, weight, means_theta, lmm, xy_out,
                       labels, X_weights, sigmas, tao, partials,
                       out, loss);
}